// Round 1
// baseline (2205.079 us; speedup 1.0000x reference)
//
#include <hip/hip_runtime.h>
#include <hip/hip_bf16.h>

#define N_NODES 50000
#define N_EDGES 1600000
#define IN_CH 128
#define HID 64
#define HID2 32

// ---------------- degree ----------------
__global__ void deg_kernel(const int* __restrict__ dst, float* __restrict__ deg, int E) {
    int e = blockIdx.x * 256 + threadIdx.x;
    if (e < E) atomicAdd(&deg[dst[e]], 1.0f);
}

__global__ void dinv_kernel(const float* __restrict__ deg, float* __restrict__ dinv, int N) {
    int i = blockIdx.x * 256 + threadIdx.x;
    if (i < N) dinv[i] = rsqrtf(deg[i] + 1.0f);
}

// ---------------- GEMM1: xw = x @ W1  (N x 128) @ (128 x 64) ----------------
__global__ __launch_bounds__(256) void gemm1_kernel(const float* __restrict__ x,
                                                    const float* __restrict__ W,
                                                    float* __restrict__ out, int N) {
    __shared__ float Ws[IN_CH * HID];   // 32 KB
    __shared__ float xs[4][IN_CH];      // 2 KB
    int tid = threadIdx.x;
    for (int i = tid; i < IN_CH * HID; i += 256) Ws[i] = W[i];
    int n0 = blockIdx.x * 4;
    for (int i = tid; i < 4 * IN_CH; i += 256) {
        int r = i / IN_CH, c = i % IN_CH;
        int n = n0 + r;
        xs[r][c] = (n < N) ? x[(size_t)n * IN_CH + c] : 0.0f;
    }
    __syncthreads();
    int r = tid / HID, j = tid % HID;
    int n = n0 + r;
    if (n < N) {
        float acc = 0.0f;
#pragma unroll 8
        for (int k = 0; k < IN_CH; k++) acc += xs[r][k] * Ws[k * HID + j];
        out[(size_t)n * HID + j] = acc;
    }
}

// ---------------- GEMM2: hw = h1 @ W2  (N x 64) @ (64 x 32) ----------------
__global__ __launch_bounds__(256) void gemm2_kernel(const float* __restrict__ h,
                                                    const float* __restrict__ W,
                                                    float* __restrict__ out, int N) {
    __shared__ float Ws[HID * HID2];    // 8 KB
    __shared__ float hs[8][HID];        // 2 KB
    int tid = threadIdx.x;
    for (int i = tid; i < HID * HID2; i += 256) Ws[i] = W[i];
    int n0 = blockIdx.x * 8;
    for (int i = tid; i < 8 * HID; i += 256) {
        int r = i / HID, c = i % HID;
        int n = n0 + r;
        hs[r][c] = (n < N) ? h[(size_t)n * HID + c] : 0.0f;
    }
    __syncthreads();
    int r = tid / HID2, j = tid % HID2;
    int n = n0 + r;
    if (n < N) {
        float acc = 0.0f;
#pragma unroll 8
        for (int k = 0; k < HID; k++) acc += hs[r][k] * Ws[k * HID2 + j];
        out[(size_t)n * HID2 + j] = acc;
    }
}

// ---------------- edge scatter: agg[dst] += feat[src] * dinv[src]*dinv[dst] ----------------
template <int F>
__global__ __launch_bounds__(256) void scatter_kernel(const int* __restrict__ src,
                                                      const int* __restrict__ dst,
                                                      const float* __restrict__ dinv,
                                                      const float* __restrict__ feat,
                                                      float* __restrict__ agg, int E) {
    const int LPE = F / 4;  // lanes per edge, each lane moves a float4
    int gid = blockIdx.x * 256 + threadIdx.x;
    int e = gid / LPE;
    if (e >= E) return;
    int lane = gid % LPE;
    int s = src[e], d = dst[e];
    float norm = dinv[s] * dinv[d];
    const float4* fv = (const float4*)(feat + (size_t)s * F);
    float4 v = fv[lane];
    float* a = agg + (size_t)d * F + lane * 4;
    atomicAdd(a + 0, v.x * norm);
    atomicAdd(a + 1, v.y * norm);
    atomicAdd(a + 2, v.z * norm);
    atomicAdd(a + 3, v.w * norm);
}

// ---------------- self-loop + bias + relu (in place into agg) ----------------
template <int F>
__global__ void selfloop_relu_kernel(float* __restrict__ agg, const float* __restrict__ feat,
                                     const float* __restrict__ dinv, const float* __restrict__ b,
                                     int N) {
    int i = blockIdx.x * 256 + threadIdx.x;
    if (i >= N * F) return;
    int n = i / F, j = i % F;
    float di = dinv[n];
    float v = agg[i] + feat[i] * di * di + b[j];
    agg[i] = v > 0.0f ? v : 0.0f;
}

// ---------------- final: h2 = relu(agg2 + hw*dinv2 + b2); out = h2 @ Wh + bh ----------------
__global__ __launch_bounds__(256) void final_kernel(const float* __restrict__ agg2,
                                                    const float* __restrict__ hw,
                                                    const float* __restrict__ dinv,
                                                    const float* __restrict__ b2,
                                                    const float* __restrict__ Wh,
                                                    const float* __restrict__ bh,
                                                    float* __restrict__ out, int N) {
    int tid = threadIdx.x;
    int n = blockIdx.x * 8 + tid / HID2;
    int j = tid % HID2;
    if (n >= N) return;
    float di = dinv[n];
    size_t idx = (size_t)n * HID2 + j;
    float v = agg2[idx] + hw[idx] * di * di + b2[j];
    v = v > 0.0f ? v : 0.0f;
    float p = v * Wh[j];
    for (int off = 16; off > 0; off >>= 1) p += __shfl_down(p, off, 32);
    if (j == 0) out[n] = p + bh[0];
}

extern "C" void kernel_launch(void* const* d_in, const int* in_sizes, int n_in,
                              void* d_out, int out_size, void* d_ws, size_t ws_size,
                              hipStream_t stream) {
    const float* x  = (const float*)d_in[0];
    const int*   ei = (const int*)d_in[1];
    const float* W1 = (const float*)d_in[2];
    const float* b1 = (const float*)d_in[3];
    const float* W2 = (const float*)d_in[4];
    const float* b2 = (const float*)d_in[5];
    const float* Wh = (const float*)d_in[6];
    const float* bh = (const float*)d_in[7];
    float* out = (float*)d_out;

    const int N = N_NODES;
    const int E = in_sizes[1] / 2;
    const int* src = ei;
    const int* dst = ei + E;

    // workspace layout (floats)
    float* ws = (float*)d_ws;
    float* deg  = ws;                       // N
    float* agg1 = ws + 50000;               // N*64
    float* agg2 = agg1 + (size_t)N * HID;   // N*32
    float* dinv = agg2 + (size_t)N * HID2;  // N
    float* xw   = dinv + 50000;             // N*64
    float* hw   = xw + (size_t)N * HID;     // N*32

    // zero deg + agg1 + agg2 (contiguous)
    size_t zero_bytes = (size_t)(50000 + (size_t)N * HID + (size_t)N * HID2) * sizeof(float);
    hipMemsetAsync(d_ws, 0, zero_bytes, stream);

    // degree + dinv
    deg_kernel<<<(E + 255) / 256, 256, 0, stream>>>(dst, deg, E);
    dinv_kernel<<<(N + 255) / 256, 256, 0, stream>>>(deg, dinv, N);

    // layer 1
    gemm1_kernel<<<(N + 3) / 4, 256, 0, stream>>>(x, W1, xw, N);
    {
        long long total = (long long)E * (HID / 4);
        int blocks = (int)((total + 255) / 256);
        scatter_kernel<HID><<<blocks, 256, 0, stream>>>(src, dst, dinv, xw, agg1, E);
    }
    selfloop_relu_kernel<HID><<<(N * HID + 255) / 256, 256, 0, stream>>>(agg1, xw, dinv, b1, N);

    // layer 2
    gemm2_kernel<<<(N + 7) / 8, 256, 0, stream>>>(agg1, W2, hw, N);
    {
        long long total = (long long)E * (HID2 / 4);
        int blocks = (int)((total + 255) / 256);
        scatter_kernel<HID2><<<blocks, 256, 0, stream>>>(src, dst, dinv, hw, agg2, E);
    }
    final_kernel<<<(N + 7) / 8, 256, 0, stream>>>(agg2, hw, dinv, b2, Wh, bh, out, N);
}

// Round 2
// 449.970 us; speedup vs baseline: 4.9005x; 4.9005x over previous
//
#include <hip/hip_runtime.h>
#include <hip/hip_bf16.h>

#define N_NODES 50000
#define N_EDGES 1600000
#define IN_CH 128
#define HID 64
#define HID2 32

// ---------------- degree histogram (in-degree over dst) ----------------
__global__ void deg_kernel(const int* __restrict__ dst, int* __restrict__ deg, int E) {
    int e = blockIdx.x * 256 + threadIdx.x;
    if (e < E) atomicAdd(&deg[dst[e]], 1);
}

__global__ void dinv_kernel(const int* __restrict__ deg, float* __restrict__ dinv, int N) {
    int i = blockIdx.x * 256 + threadIdx.x;
    if (i < N) dinv[i] = rsqrtf((float)deg[i] + 1.0f);
}

// ---------------- single-block exclusive scan over deg -> off ----------------
__global__ __launch_bounds__(1024) void scan_kernel(const int* __restrict__ deg,
                                                    int* __restrict__ off, int N) {
    __shared__ int wsum[16];
    __shared__ int carry_s, total_s;
    int tid = threadIdx.x, lane = tid & 63, wid = tid >> 6;
    if (tid == 0) carry_s = 0;
    __syncthreads();
    for (int base = 0; base < N; base += 1024) {
        int i = base + tid;
        int v = (i < N) ? deg[i] : 0;
        int s = v;
#pragma unroll
        for (int d = 1; d < 64; d <<= 1) {
            int t = __shfl_up(s, d, 64);
            if (lane >= d) s += t;
        }
        if (lane == 63) wsum[wid] = s;
        __syncthreads();
        if (tid == 0) {
            int run = 0;
            for (int w = 0; w < 16; w++) { int t = wsum[w]; wsum[w] = run; run += t; }
            total_s = run;
        }
        __syncthreads();
        if (i < N) off[i] = carry_s + wsum[wid] + s - v;  // exclusive
        __syncthreads();
        if (tid == 0) carry_s += total_s;
        __syncthreads();
    }
}

// ---------------- bucket edges by dst: sorted_src[pos] = src ----------------
__global__ void sort_kernel(const int* __restrict__ src, const int* __restrict__ dst,
                            const int* __restrict__ off, int* __restrict__ cursor,
                            int* __restrict__ sorted_src, int E) {
    int e = blockIdx.x * 256 + threadIdx.x;
    if (e >= E) return;
    int d = dst[e];
    int pos = off[d] + atomicAdd(&cursor[d], 1);
    sorted_src[pos] = src[e];
}

// ---------------- GEMM1: xw = x @ W1  (N x 128) @ (128 x 64) ----------------
__global__ __launch_bounds__(256) void gemm1_kernel(const float* __restrict__ x,
                                                    const float* __restrict__ W,
                                                    float* __restrict__ out, int N) {
    __shared__ float Ws[IN_CH * HID];   // 32 KB
    __shared__ float xs[4][IN_CH];      // 2 KB
    int tid = threadIdx.x;
    for (int i = tid; i < IN_CH * HID; i += 256) Ws[i] = W[i];
    int n0 = blockIdx.x * 4;
    for (int i = tid; i < 4 * IN_CH; i += 256) {
        int r = i / IN_CH, c = i % IN_CH;
        int n = n0 + r;
        xs[r][c] = (n < N) ? x[(size_t)n * IN_CH + c] : 0.0f;
    }
    __syncthreads();
    int r = tid / HID, j = tid % HID;
    int n = n0 + r;
    if (n < N) {
        float acc = 0.0f;
#pragma unroll 8
        for (int k = 0; k < IN_CH; k++) acc += xs[r][k] * Ws[k * HID + j];
        out[(size_t)n * HID + j] = acc;
    }
}

// ---------------- GEMM2: hw = h1 @ W2  (N x 64) @ (64 x 32) ----------------
__global__ __launch_bounds__(256) void gemm2_kernel(const float* __restrict__ h,
                                                    const float* __restrict__ W,
                                                    float* __restrict__ out, int N) {
    __shared__ float Ws[HID * HID2];    // 8 KB
    __shared__ float hs[8][HID];        // 2 KB
    int tid = threadIdx.x;
    for (int i = tid; i < HID * HID2; i += 256) Ws[i] = W[i];
    int n0 = blockIdx.x * 8;
    for (int i = tid; i < 8 * HID; i += 256) {
        int r = i / HID, c = i % HID;
        int n = n0 + r;
        hs[r][c] = (n < N) ? h[(size_t)n * HID + c] : 0.0f;
    }
    __syncthreads();
    int r = tid / HID2, j = tid % HID2;
    int n = n0 + r;
    if (n < N) {
        float acc = 0.0f;
#pragma unroll 8
        for (int k = 0; k < HID; k++) acc += hs[r][k] * Ws[k * HID2 + j];
        out[(size_t)n * HID2 + j] = acc;
    }
}

// ---------------- layer-1 aggregate: wave per node, F=64 ----------------
// h1[n] = relu( dinv[n] * sum_e dinv[s_e]*xw[s_e] + dinv[n]^2 * xw[n] + b1 )
__global__ __launch_bounds__(256) void agg1_kernel(const int* __restrict__ sorted_src,
                                                   const int* __restrict__ off,
                                                   const int* __restrict__ deg,
                                                   const float* __restrict__ dinv,
                                                   const float* __restrict__ xw,
                                                   const float* __restrict__ b1,
                                                   float* __restrict__ h1, int N) {
    int lane = threadIdx.x & 63;
    int n = blockIdx.x * 4 + (threadIdx.x >> 6);
    if (n >= N) return;
    int g = lane >> 4, fl = lane & 15;            // 4 edge-groups x 16 feature-lanes
    int start = off[n], end = start + deg[n];
    float ax = 0.f, ay = 0.f, az = 0.f, aw = 0.f;
    for (int i = start + g; i < end; i += 4) {
        int s = sorted_src[i];
        float ns = dinv[s];
        float4 v = *(const float4*)(xw + (size_t)s * HID + fl * 4);
        ax += v.x * ns; ay += v.y * ns; az += v.z * ns; aw += v.w * ns;
    }
    // reduce the 4 edge-groups (lanes fl, fl+16, fl+32, fl+48)
    ax += __shfl_xor(ax, 16, 64); ay += __shfl_xor(ay, 16, 64);
    az += __shfl_xor(az, 16, 64); aw += __shfl_xor(aw, 16, 64);
    ax += __shfl_xor(ax, 32, 64); ay += __shfl_xor(ay, 32, 64);
    az += __shfl_xor(az, 32, 64); aw += __shfl_xor(aw, 32, 64);
    if (g == 0) {
        float di = dinv[n], di2 = di * di;
        float4 sv = *(const float4*)(xw + (size_t)n * HID + fl * 4);
        float4 bb = *(const float4*)(b1 + fl * 4);
        float4 o;
        o.x = fmaxf(ax * di + sv.x * di2 + bb.x, 0.f);
        o.y = fmaxf(ay * di + sv.y * di2 + bb.y, 0.f);
        o.z = fmaxf(az * di + sv.z * di2 + bb.z, 0.f);
        o.w = fmaxf(aw * di + sv.w * di2 + bb.w, 0.f);
        *(float4*)(h1 + (size_t)n * HID + fl * 4) = o;
    }
}

// ---------------- layer-2 aggregate + head: wave per node, F=32 ----------------
// h2 = relu( dinv[n]*sum dinv[s]*hw[s] + dinv[n]^2*hw[n] + b2 ); out[n] = h2 . Wh + bh
__global__ __launch_bounds__(256) void agg2_final_kernel(const int* __restrict__ sorted_src,
                                                         const int* __restrict__ off,
                                                         const int* __restrict__ deg,
                                                         const float* __restrict__ dinv,
                                                         const float* __restrict__ hw,
                                                         const float* __restrict__ b2,
                                                         const float* __restrict__ Wh,
                                                         const float* __restrict__ bh,
                                                         float* __restrict__ out, int N) {
    int lane = threadIdx.x & 63;
    int n = blockIdx.x * 4 + (threadIdx.x >> 6);
    if (n >= N) return;
    int g = lane >> 3, fl = lane & 7;             // 8 edge-groups x 8 feature-lanes
    int start = off[n], end = start + deg[n];
    float ax = 0.f, ay = 0.f, az = 0.f, aw = 0.f;
    for (int i = start + g; i < end; i += 8) {
        int s = sorted_src[i];
        float ns = dinv[s];
        float4 v = *(const float4*)(hw + (size_t)s * HID2 + fl * 4);
        ax += v.x * ns; ay += v.y * ns; az += v.z * ns; aw += v.w * ns;
    }
#pragma unroll
    for (int m = 8; m <= 32; m <<= 1) {
        ax += __shfl_xor(ax, m, 64); ay += __shfl_xor(ay, m, 64);
        az += __shfl_xor(az, m, 64); aw += __shfl_xor(aw, m, 64);
    }
    // all lanes now hold the full sums for their fl quad; compute head on all lanes
    float di = dinv[n], di2 = di * di;
    float4 sv = *(const float4*)(hw + (size_t)n * HID2 + fl * 4);
    float4 bb = *(const float4*)(b2 + fl * 4);
    float4 wv = *(const float4*)(Wh + fl * 4);
    float p = fmaxf(ax * di + sv.x * di2 + bb.x, 0.f) * wv.x
            + fmaxf(ay * di + sv.y * di2 + bb.y, 0.f) * wv.y
            + fmaxf(az * di + sv.z * di2 + bb.z, 0.f) * wv.z
            + fmaxf(aw * di + sv.w * di2 + bb.w, 0.f) * wv.w;
    p += __shfl_xor(p, 1, 64);
    p += __shfl_xor(p, 2, 64);
    p += __shfl_xor(p, 4, 64);
    if (lane == 0) out[n] = p + bh[0];
}

extern "C" void kernel_launch(void* const* d_in, const int* in_sizes, int n_in,
                              void* d_out, int out_size, void* d_ws, size_t ws_size,
                              hipStream_t stream) {
    const float* x  = (const float*)d_in[0];
    const int*   ei = (const int*)d_in[1];
    const float* W1 = (const float*)d_in[2];
    const float* b1 = (const float*)d_in[3];
    const float* W2 = (const float*)d_in[4];
    const float* b2 = (const float*)d_in[5];
    const float* Wh = (const float*)d_in[6];
    const float* bh = (const float*)d_in[7];
    float* out = (float*)d_out;

    const int N = N_NODES;
    const int E = in_sizes[1] / 2;
    const int* src = ei;
    const int* dst = ei + E;

    // workspace layout (all 4-byte elements), deg+cursor first so one memset zeroes both
    const int NP = 50176;  // padded N
    char* ws = (char*)d_ws;
    int*   deg    = (int*)ws;                         // NP
    int*   cursor = deg + NP;                         // NP
    int*   off    = cursor + NP;                      // NP
    float* dinv   = (float*)(off + NP);               // NP
    int*   sorted = (int*)(dinv + NP);                // E
    float* xw     = (float*)(sorted + E);             // N*64
    float* h1     = xw + (size_t)N * HID;             // N*64
    float* hw     = h1 + (size_t)N * HID;             // N*32

    // zero deg + cursor (contiguous, 2*NP ints)
    hipMemsetAsync(deg, 0, (size_t)2 * NP * sizeof(int), stream);

    // CSR build
    deg_kernel<<<(E + 255) / 256, 256, 0, stream>>>(dst, deg, E);
    dinv_kernel<<<(N + 255) / 256, 256, 0, stream>>>(deg, dinv, N);
    scan_kernel<<<1, 1024, 0, stream>>>(deg, off, N);
    sort_kernel<<<(E + 255) / 256, 256, 0, stream>>>(src, dst, off, cursor, sorted, E);

    // layer 1
    gemm1_kernel<<<(N + 3) / 4, 256, 0, stream>>>(x, W1, xw, N);
    agg1_kernel<<<(N + 3) / 4, 256, 0, stream>>>(sorted, off, deg, dinv, xw, b1, h1, N);

    // layer 2 + head
    gemm2_kernel<<<(N + 7) / 8, 256, 0, stream>>>(h1, W2, hw, N);
    agg2_final_kernel<<<(N + 3) / 4, 256, 0, stream>>>(sorted, off, deg, dinv, hw, b2, Wh, bh, out, N);
}

// Round 4
// 291.636 us; speedup vs baseline: 7.5611x; 1.5429x over previous
//
#include <hip/hip_runtime.h>
#include <hip/hip_bf16.h>

#define N_NODES 50000
#define IN_CH 128
#define HID 64
#define HID2 32

constexpr int NB = 391;      // coarse buckets of 128 nodes: ceil(50000/128)
constexpr int CHUNK = 4096;  // edges per binning block
constexpr int CAP = 5120;    // max edges per bucket (mean 4096, sigma ~64)

// ---------------- A0: coarse histogram of dst>>7 (LDS-private) ----------------
__global__ __launch_bounds__(256) void coarse_hist_kernel(const int* __restrict__ dst,
                                                          int* __restrict__ bhist, int E) {
    __shared__ int h[NB];
    int tid = threadIdx.x;
    for (int i = tid; i < NB; i += 256) h[i] = 0;
    __syncthreads();
    int base = blockIdx.x * CHUNK;
#pragma unroll
    for (int k = 0; k < CHUNK / 256; k++) {
        int e = base + k * 256 + tid;
        if (e < E) atomicAdd(&h[dst[e] >> 7], 1);
    }
    __syncthreads();
    for (int i = tid; i < NB; i += 256) if (h[i]) atomicAdd(&bhist[i], h[i]);
}

// ---------------- scan of NB bucket counts (one block) ----------------
__global__ __launch_bounds__(256) void coarse_scan_kernel(const int* __restrict__ bhist,
                                                          int* __restrict__ bbase,
                                                          int* __restrict__ bcur,
                                                          int* __restrict__ off, int E) {
    __shared__ int sh[NB + 1];
    int tid = threadIdx.x;
    for (int i = tid; i < NB; i += 256) sh[i] = bhist[i];
    __syncthreads();
    if (tid == 0) {
        int run = 0;
        for (int b = 0; b < NB; b++) { int t = sh[b]; sh[b] = run; run += t; }
        sh[NB] = run;
        off[N_NODES] = run;  // == E
    }
    __syncthreads();
    for (int i = tid; i <= NB; i += 256) {
        bbase[i] = sh[i];
        if (i < NB) bcur[i] = sh[i];
    }
}

// ---------------- A1: bin edges into coarse buckets, bucket-grouped writes ----
// psrc[gp] = src;  pdst[gp] = (edge_id << 7) | (dst & 127)   (id<2^21 -> 28 bits)
__global__ __launch_bounds__(256) void bin_kernel(const int* __restrict__ src,
                                                  const int* __restrict__ dst,
                                                  int* __restrict__ bcur,
                                                  int* __restrict__ psrc,
                                                  int* __restrict__ pdst, int E) {
    __shared__ int hist[NB], lbase[NB], gbase[NB], lcur[NB];
    __shared__ int outs[CHUNK], outd[CHUNK], outi[CHUNK];
    int tid = threadIdx.x;
    int base = blockIdx.x * CHUNK;
    int cnt = min(CHUNK, E - base);
    for (int i = tid; i < NB; i += 256) hist[i] = 0;
    int es[CHUNK / 256], ed[CHUNK / 256];
    __syncthreads();
#pragma unroll
    for (int k = 0; k < CHUNK / 256; k++) {
        int e = base + k * 256 + tid;
        if (e < E) {
            es[k] = src[e];
            ed[k] = dst[e];
            atomicAdd(&hist[ed[k] >> 7], 1);
        }
    }
    __syncthreads();
    if (tid == 0) {
        int run = 0;
        for (int b = 0; b < NB; b++) { int t = hist[b]; lbase[b] = run; run += t; }
    }
    __syncthreads();
    for (int i = tid; i < NB; i += 256) {
        gbase[i] = hist[i] ? atomicAdd(&bcur[i], hist[i]) : 0;
        lcur[i] = lbase[i];
    }
    __syncthreads();
#pragma unroll
    for (int k = 0; k < CHUNK / 256; k++) {
        int e = base + k * 256 + tid;
        if (e < E) {
            int b = ed[k] >> 7;
            int p = atomicAdd(&lcur[b], 1);
            outs[p] = es[k];
            outd[p] = ed[k];
            outi[p] = e;
        }
    }
    __syncthreads();
#pragma unroll
    for (int k = 0; k < CHUNK / 256; k++) {
        int i = k * 256 + tid;
        if (i < cnt) {
            int d = outd[i];
            int b = d >> 7;
            int gp = gbase[b] + (i - lbase[b]);
            psrc[gp] = outs[i];
            pdst[gp] = (outi[i] << 7) | (d & 127);
        }
    }
}

// ---------------- B: per-bucket fine pass; deterministic rank-by-edge-id ------
// emits sorted_src (into psrc, each node's edges in original edge order), off, dinv
__global__ __launch_bounds__(256) void fine_kernel(int* __restrict__ psrc,
                                                   const int* __restrict__ pdst,
                                                   const int* __restrict__ bbase,
                                                   int* __restrict__ off,
                                                   float* __restrict__ dinv, int N) {
    __shared__ int gkey[CAP], gsrc[CAP];
    __shared__ int fh[128], fb[128], fc[128];
    int b = blockIdx.x, tid = threadIdx.x;
    int gb = bbase[b];
    int cnt = bbase[b + 1] - gb;
    if (cnt > CAP) cnt = CAP;  // statistically impossible; safety clamp
    if (tid < 128) fh[tid] = 0;
    __syncthreads();
    // pass A: per-node histogram
    for (int i = tid; i < cnt; i += 256) atomicAdd(&fh[pdst[gb + i] & 127], 1);
    __syncthreads();
    if (tid == 0) {
        int run = 0;
        for (int j = 0; j < 128; j++) { int t = fh[j]; fb[j] = run; run += t; }
    }
    __syncthreads();
    if (tid < 128) {
        fc[tid] = fb[tid];
        int node = (b << 7) + tid;
        if (node < N) {
            off[node] = gb + fb[tid];
            dinv[node] = rsqrtf((float)fh[tid] + 1.0f);
        }
    }
    __syncthreads();
    // pass B: scatter (key, src) into node segments (arbitrary order within segment)
    for (int i = tid; i < cnt; i += 256) {
        int v = pdst[gb + i], s = psrc[gb + i];
        int p = atomicAdd(&fc[v & 127], 1);
        gkey[p] = v;
        gsrc[p] = s;
    }
    __syncthreads();
    // pass C: rank by key (edge id in high bits, unique) -> deterministic order
    for (int i = tid; i < cnt; i += 256) {
        int v = gkey[i], dl = v & 127;
        int b0 = fb[dl], L = fh[dl];
        int r = 0;
        for (int j = b0; j < b0 + L; j++) r += (gkey[j] < v) ? 1 : 0;
        psrc[gb + b0 + r] = gsrc[i];
    }
}

// ---------------- register-blocked small GEMM: out[N,J] = X[N,K] @ W[K,J] ----------------
template <int K, int J, int NPB>
__global__ __launch_bounds__(256) void gemm_rb_kernel(const float* __restrict__ X,
                                                      const float* __restrict__ W,
                                                      float* __restrict__ out, int N) {
    __shared__ float Ws[K * J];
    __shared__ float xs[NPB][K + 1];
    int tid = threadIdx.x;
    for (int i = tid; i < K * J / 4; i += 256) ((float4*)Ws)[i] = ((const float4*)W)[i];
    int n0 = blockIdx.x * NPB;
    for (int i = tid; i < NPB * (K / 4); i += 256) {
        int r = i / (K / 4), c = i % (K / 4);
        int n = n0 + r;
        float4 v = make_float4(0.f, 0.f, 0.f, 0.f);
        if (n < N) v = ((const float4*)(X + (size_t)n * K))[c];
        *(float4*)&xs[r][c * 4] = v;
    }
    __syncthreads();
    constexpr int QJ = J / 4;
    int q = tid % QJ, g = (tid / QJ) * 2;
    float4 a0 = make_float4(0.f, 0.f, 0.f, 0.f);
    float4 a1 = make_float4(0.f, 0.f, 0.f, 0.f);
#pragma unroll 8
    for (int k = 0; k < K; k++) {
        float4 w = *(const float4*)&Ws[k * J + q * 4];
        float x0 = xs[g][k], x1 = xs[g + 1][k];
        a0.x += x0 * w.x; a0.y += x0 * w.y; a0.z += x0 * w.z; a0.w += x0 * w.w;
        a1.x += x1 * w.x; a1.y += x1 * w.y; a1.z += x1 * w.z; a1.w += x1 * w.w;
    }
    int n = n0 + g;
    if (n < N)     *(float4*)(out + (size_t)n * J + q * 4) = a0;
    if (n + 1 < N) *(float4*)(out + (size_t)(n + 1) * J + q * 4) = a1;
}

// ---------------- layer-1 aggregate: wave per node, F=64 ----------------
__global__ __launch_bounds__(256) void agg1_kernel(const int* __restrict__ sorted_src,
                                                   const int* __restrict__ off,
                                                   const float* __restrict__ dinv,
                                                   const float* __restrict__ xw,
                                                   const float* __restrict__ b1,
                                                   float* __restrict__ h1, int N) {
    int lane = threadIdx.x & 63;
    int n = blockIdx.x * 4 + (threadIdx.x >> 6);
    if (n >= N) return;
    int g = lane >> 4, fl = lane & 15;  // 4 edge-groups x 16 feature-lanes
    int start = off[n], end = off[n + 1];
    float ax = 0.f, ay = 0.f, az = 0.f, aw = 0.f;
    for (int i = start + g; i < end; i += 4) {
        int s = sorted_src[i];
        float ns = dinv[s];
        float4 v = *(const float4*)(xw + (size_t)s * HID + fl * 4);
        ax += v.x * ns; ay += v.y * ns; az += v.z * ns; aw += v.w * ns;
    }
    ax += __shfl_xor(ax, 16, 64); ay += __shfl_xor(ay, 16, 64);
    az += __shfl_xor(az, 16, 64); aw += __shfl_xor(aw, 16, 64);
    ax += __shfl_xor(ax, 32, 64); ay += __shfl_xor(ay, 32, 64);
    az += __shfl_xor(az, 32, 64); aw += __shfl_xor(aw, 32, 64);
    if (g == 0) {
        float di = dinv[n], di2 = di * di;
        float4 sv = *(const float4*)(xw + (size_t)n * HID + fl * 4);
        float4 bb = *(const float4*)(b1 + fl * 4);
        float4 o;
        o.x = fmaxf(ax * di + sv.x * di2 + bb.x, 0.f);
        o.y = fmaxf(ay * di + sv.y * di2 + bb.y, 0.f);
        o.z = fmaxf(az * di + sv.z * di2 + bb.z, 0.f);
        o.w = fmaxf(aw * di + sv.w * di2 + bb.w, 0.f);
        *(float4*)(h1 + (size_t)n * HID + fl * 4) = o;
    }
}

// ---------------- layer-2 aggregate + head: wave per node, F=32 ----------------
__global__ __launch_bounds__(256) void agg2_final_kernel(const int* __restrict__ sorted_src,
                                                         const int* __restrict__ off,
                                                         const float* __restrict__ dinv,
                                                         const float* __restrict__ hw,
                                                         const float* __restrict__ b2,
                                                         const float* __restrict__ Wh,
                                                         const float* __restrict__ bh,
                                                         float* __restrict__ out, int N) {
    int lane = threadIdx.x & 63;
    int n = blockIdx.x * 4 + (threadIdx.x >> 6);
    if (n >= N) return;
    int g = lane >> 3, fl = lane & 7;  // 8 edge-groups x 8 feature-lanes
    int start = off[n], end = off[n + 1];
    float ax = 0.f, ay = 0.f, az = 0.f, aw = 0.f;
    for (int i = start + g; i < end; i += 8) {
        int s = sorted_src[i];
        float ns = dinv[s];
        float4 v = *(const float4*)(hw + (size_t)s * HID2 + fl * 4);
        ax += v.x * ns; ay += v.y * ns; az += v.z * ns; aw += v.w * ns;
    }
#pragma unroll
    for (int m = 8; m <= 32; m <<= 1) {
        ax += __shfl_xor(ax, m, 64); ay += __shfl_xor(ay, m, 64);
        az += __shfl_xor(az, m, 64); aw += __shfl_xor(aw, m, 64);
    }
    float di = dinv[n], di2 = di * di;
    float4 sv = *(const float4*)(hw + (size_t)n * HID2 + fl * 4);
    float4 bb = *(const float4*)(b2 + fl * 4);
    float4 wv = *(const float4*)(Wh + fl * 4);
    float p = fmaxf(ax * di + sv.x * di2 + bb.x, 0.f) * wv.x
            + fmaxf(ay * di + sv.y * di2 + bb.y, 0.f) * wv.y
            + fmaxf(az * di + sv.z * di2 + bb.z, 0.f) * wv.z
            + fmaxf(aw * di + sv.w * di2 + bb.w, 0.f) * wv.w;
    p += __shfl_xor(p, 1, 64);
    p += __shfl_xor(p, 2, 64);
    p += __shfl_xor(p, 4, 64);
    if (lane == 0) out[n] = p + bh[0];
}

extern "C" void kernel_launch(void* const* d_in, const int* in_sizes, int n_in,
                              void* d_out, int out_size, void* d_ws, size_t ws_size,
                              hipStream_t stream) {
    const float* x  = (const float*)d_in[0];
    const int*   ei = (const int*)d_in[1];
    const float* W1 = (const float*)d_in[2];
    const float* b1 = (const float*)d_in[3];
    const float* W2 = (const float*)d_in[4];
    const float* b2 = (const float*)d_in[5];
    const float* Wh = (const float*)d_in[6];
    const float* bh = (const float*)d_in[7];
    float* out = (float*)d_out;

    const int N = N_NODES;
    const int E = in_sizes[1] / 2;
    const int* src = ei;
    const int* dst = ei + E;

    // workspace layout (4-byte units) — total ~38.8 MB
    int* ws = (int*)d_ws;
    int*   bhist = ws;                       // NB (pad 400)
    int*   bbase = bhist + 400;              // NB+1 (pad 400)
    int*   bcur  = bbase + 400;              // NB (pad 400)
    int*   off   = bcur + 400;               // N+1 (pad 50048)
    float* dinv  = (float*)(off + 50048);    // N (pad 50048)
    int*   psrc  = (int*)(dinv + 50048);     // E  (becomes sorted_src)
    int*   pdst  = psrc + E;                 // E  (packed id<<7 | dst&127)
    float* xw    = (float*)(pdst + E);       // N*64
    float* h1    = xw + (size_t)N * HID;     // N*64
    float* hw    = xw;                       // alias: xw dead after agg1

    hipMemsetAsync(bhist, 0, NB * sizeof(int), stream);

    int eblocks = (E + CHUNK - 1) / CHUNK;
    coarse_hist_kernel<<<eblocks, 256, 0, stream>>>(dst, bhist, E);
    coarse_scan_kernel<<<1, 256, 0, stream>>>(bhist, bbase, bcur, off, E);
    bin_kernel<<<eblocks, 256, 0, stream>>>(src, dst, bcur, psrc, pdst, E);
    fine_kernel<<<NB, 256, 0, stream>>>(psrc, pdst, bbase, off, dinv, N);

    // layer 1
    gemm_rb_kernel<IN_CH, HID, 32><<<(N + 31) / 32, 256, 0, stream>>>(x, W1, xw, N);
    agg1_kernel<<<(N + 3) / 4, 256, 0, stream>>>(psrc, off, dinv, xw, b1, h1, N);

    // layer 2 + head
    gemm_rb_kernel<HID, HID2, 64><<<(N + 63) / 64, 256, 0, stream>>>(h1, W2, hw, N);
    agg2_final_kernel<<<(N + 3) / 4, 256, 0, stream>>>(psrc, off, dinv, hw, b2, Wh, bh, out, N);
}

// Round 5
// 251.669 us; speedup vs baseline: 8.7618x; 1.1588x over previous
//
#include <hip/hip_runtime.h>
#include <hip/hip_bf16.h>

#define N_NODES 50000
#define IN_CH 128
#define HID 64
#define HID2 32

constexpr int NB = 391;      // coarse buckets of 128 nodes: ceil(50000/128)
constexpr int CHUNK = 4096;  // edges per binning block
constexpr int CAP = 5120;    // max edges per bucket (mean 4096, sigma ~64)

__device__ __forceinline__ unsigned short f2bf(float f) {
    union { float f; unsigned u; } v; v.f = f;
    unsigned r = v.u + 0x7fff + ((v.u >> 16) & 1);  // RNE
    return (unsigned short)(r >> 16);
}
__device__ __forceinline__ float bflo(unsigned d) {  // low 16 bits -> fp32
    union { unsigned u; float f; } v; v.u = d << 16; return v.f;
}
__device__ __forceinline__ float bfhi(unsigned d) {  // high 16 bits -> fp32
    union { unsigned u; float f; } v; v.u = d & 0xffff0000u; return v.f;
}

// ---------------- A0: coarse histogram of dst>>7 (LDS-private) ----------------
__global__ __launch_bounds__(256) void coarse_hist_kernel(const int* __restrict__ dst,
                                                          int* __restrict__ bhist, int E) {
    __shared__ int h[NB];
    int tid = threadIdx.x;
    for (int i = tid; i < NB; i += 256) h[i] = 0;
    __syncthreads();
    int base = blockIdx.x * CHUNK;
#pragma unroll
    for (int k = 0; k < CHUNK / 256; k++) {
        int e = base + k * 256 + tid;
        if (e < E) atomicAdd(&h[dst[e] >> 7], 1);
    }
    __syncthreads();
    for (int i = tid; i < NB; i += 256) if (h[i]) atomicAdd(&bhist[i], h[i]);
}

// ---------------- scan of NB bucket counts (one block) ----------------
__global__ __launch_bounds__(256) void coarse_scan_kernel(const int* __restrict__ bhist,
                                                          int* __restrict__ bbase,
                                                          int* __restrict__ bcur,
                                                          int* __restrict__ off, int E) {
    __shared__ int sh[NB + 1];
    int tid = threadIdx.x;
    for (int i = tid; i < NB; i += 256) sh[i] = bhist[i];
    __syncthreads();
    if (tid == 0) {
        int run = 0;
        for (int b = 0; b < NB; b++) { int t = sh[b]; sh[b] = run; run += t; }
        sh[NB] = run;
        off[N_NODES] = run;  // == E
    }
    __syncthreads();
    for (int i = tid; i <= NB; i += 256) {
        bbase[i] = sh[i];
        if (i < NB) bcur[i] = sh[i];
    }
}

// ---------------- A1: bin edges into coarse buckets, bucket-grouped writes ----
// psrc[gp] = src (ushort);  pdst[gp] = (edge_id << 7) | (dst & 127)
__global__ __launch_bounds__(256) void bin_kernel(const int* __restrict__ src,
                                                  const int* __restrict__ dst,
                                                  int* __restrict__ bcur,
                                                  unsigned short* __restrict__ psrc,
                                                  int* __restrict__ pdst, int E) {
    __shared__ int hist[NB], lbase[NB], gbase[NB], lcur[NB];
    __shared__ unsigned short outs[CHUNK];
    __shared__ int outd[CHUNK], outi[CHUNK];
    int tid = threadIdx.x;
    int base = blockIdx.x * CHUNK;
    int cnt = min(CHUNK, E - base);
    for (int i = tid; i < NB; i += 256) hist[i] = 0;
    int es[CHUNK / 256], ed[CHUNK / 256];
    __syncthreads();
#pragma unroll
    for (int k = 0; k < CHUNK / 256; k++) {
        int e = base + k * 256 + tid;
        if (e < E) {
            es[k] = src[e];
            ed[k] = dst[e];
            atomicAdd(&hist[ed[k] >> 7], 1);
        }
    }
    __syncthreads();
    if (tid == 0) {
        int run = 0;
        for (int b = 0; b < NB; b++) { int t = hist[b]; lbase[b] = run; run += t; }
    }
    __syncthreads();
    for (int i = tid; i < NB; i += 256) {
        gbase[i] = hist[i] ? atomicAdd(&bcur[i], hist[i]) : 0;
        lcur[i] = lbase[i];
    }
    __syncthreads();
#pragma unroll
    for (int k = 0; k < CHUNK / 256; k++) {
        int e = base + k * 256 + tid;
        if (e < E) {
            int b = ed[k] >> 7;
            int p = atomicAdd(&lcur[b], 1);
            outs[p] = (unsigned short)es[k];
            outd[p] = ed[k];
            outi[p] = e;
        }
    }
    __syncthreads();
#pragma unroll
    for (int k = 0; k < CHUNK / 256; k++) {
        int i = k * 256 + tid;
        if (i < cnt) {
            int d = outd[i];
            int b = d >> 7;
            int gp = gbase[b] + (i - lbase[b]);
            psrc[gp] = outs[i];
            pdst[gp] = (outi[i] << 7) | (d & 127);
        }
    }
}

// ---------------- B: per-bucket fine pass; deterministic rank-by-edge-id ------
__global__ __launch_bounds__(256) void fine_kernel(unsigned short* __restrict__ psrc,
                                                   const int* __restrict__ pdst,
                                                   const int* __restrict__ bbase,
                                                   int* __restrict__ off,
                                                   float* __restrict__ dinv, int N) {
    __shared__ int gkey[CAP];
    __shared__ unsigned short gsrc[CAP];
    __shared__ int fh[128], fb[128], fc[128];
    int b = blockIdx.x, tid = threadIdx.x;
    int gb = bbase[b];
    int cnt = bbase[b + 1] - gb;
    if (cnt > CAP) cnt = CAP;  // statistically impossible; safety clamp
    if (tid < 128) fh[tid] = 0;
    __syncthreads();
    for (int i = tid; i < cnt; i += 256) atomicAdd(&fh[pdst[gb + i] & 127], 1);
    __syncthreads();
    if (tid == 0) {
        int run = 0;
        for (int j = 0; j < 128; j++) { int t = fh[j]; fb[j] = run; run += t; }
    }
    __syncthreads();
    if (tid < 128) {
        fc[tid] = fb[tid];
        int node = (b << 7) + tid;
        if (node < N) {
            off[node] = gb + fb[tid];
            dinv[node] = rsqrtf((float)fh[tid] + 1.0f);
        }
    }
    __syncthreads();
    for (int i = tid; i < cnt; i += 256) {
        int v = pdst[gb + i];
        unsigned short s = psrc[gb + i];
        int p = atomicAdd(&fc[v & 127], 1);
        gkey[p] = v;
        gsrc[p] = s;
    }
    __syncthreads();
    for (int i = tid; i < cnt; i += 256) {
        int v = gkey[i], dl = v & 127;
        int b0 = fb[dl], L = fh[dl];
        int r = 0;
        for (int j = b0; j < b0 + L; j++) r += (gkey[j] < v) ? 1 : 0;
        psrc[gb + b0 + r] = gsrc[i];
    }
}

// ---- register-blocked small GEMM with fused dinv-scale + bf16 epilogue ----
// out_bf16[n][j] = bf16( dinv[n] * (X@W)[n][j] )
template <int K, int J, int NPB>
__global__ __launch_bounds__(256) void gemm_rb_bf16_kernel(const float* __restrict__ X,
                                                           const float* __restrict__ W,
                                                           const float* __restrict__ dinv,
                                                           unsigned short* __restrict__ out, int N) {
    __shared__ float Ws[K * J];
    __shared__ float xs[NPB][K + 1];
    int tid = threadIdx.x;
    for (int i = tid; i < K * J / 4; i += 256) ((float4*)Ws)[i] = ((const float4*)W)[i];
    int n0 = blockIdx.x * NPB;
    for (int i = tid; i < NPB * (K / 4); i += 256) {
        int r = i / (K / 4), c = i % (K / 4);
        int n = n0 + r;
        float4 v = make_float4(0.f, 0.f, 0.f, 0.f);
        if (n < N) v = ((const float4*)(X + (size_t)n * K))[c];
        *(float4*)&xs[r][c * 4] = v;
    }
    __syncthreads();
    constexpr int QJ = J / 4;
    int q = tid % QJ, g = (tid / QJ) * 2;
    float4 a0 = make_float4(0.f, 0.f, 0.f, 0.f);
    float4 a1 = make_float4(0.f, 0.f, 0.f, 0.f);
#pragma unroll 8
    for (int k = 0; k < K; k++) {
        float4 w = *(const float4*)&Ws[k * J + q * 4];
        float x0 = xs[g][k], x1 = xs[g + 1][k];
        a0.x += x0 * w.x; a0.y += x0 * w.y; a0.z += x0 * w.z; a0.w += x0 * w.w;
        a1.x += x1 * w.x; a1.y += x1 * w.y; a1.z += x1 * w.z; a1.w += x1 * w.w;
    }
    int n = n0 + g;
    if (n < N) {
        float d0 = dinv[n];
        ushort4 o = make_ushort4(f2bf(a0.x * d0), f2bf(a0.y * d0),
                                 f2bf(a0.z * d0), f2bf(a0.w * d0));
        *(ushort4*)(out + (size_t)n * J + q * 4) = o;
    }
    if (n + 1 < N) {
        float d1 = dinv[n + 1];
        ushort4 o = make_ushort4(f2bf(a1.x * d1), f2bf(a1.y * d1),
                                 f2bf(a1.z * d1), f2bf(a1.w * d1));
        *(ushort4*)(out + (size_t)(n + 1) * J + q * 4) = o;
    }
}

// ---------------- layer-1 aggregate: wave per node, F=64, bf16 table ----------
// h1[n] = relu( dinv[n] * (sum_s xws[s] + xws[n]) + b1 )
__global__ __launch_bounds__(256) void agg1_kernel(const unsigned short* __restrict__ sorted_src,
                                                   const int* __restrict__ off,
                                                   const float* __restrict__ dinv,
                                                   const unsigned short* __restrict__ xws,
                                                   const float* __restrict__ b1,
                                                   float* __restrict__ h1, int N) {
    int lane = threadIdx.x & 63;
    int n = blockIdx.x * 4 + (threadIdx.x >> 6);
    if (n >= N) return;
    int g = lane >> 3, fl = lane & 7;  // 8 edge-groups x 8 feature-lanes
    int start = off[n], end = off[n + 1];
    float acc[8] = {0.f, 0.f, 0.f, 0.f, 0.f, 0.f, 0.f, 0.f};
    for (int i = start + g; i < end; i += 8) {
        int s = sorted_src[i];
        uint4 q = *(const uint4*)(xws + (size_t)s * HID + fl * 8);
        acc[0] += bflo(q.x); acc[1] += bfhi(q.x);
        acc[2] += bflo(q.y); acc[3] += bfhi(q.y);
        acc[4] += bflo(q.z); acc[5] += bfhi(q.z);
        acc[6] += bflo(q.w); acc[7] += bfhi(q.w);
    }
#pragma unroll
    for (int m = 8; m <= 32; m <<= 1)
#pragma unroll
        for (int j = 0; j < 8; j++) acc[j] += __shfl_xor(acc[j], m, 64);
    if (g == 0) {
        float di = dinv[n];
        uint4 q = *(const uint4*)(xws + (size_t)n * HID + fl * 8);
        float sv[8] = {bflo(q.x), bfhi(q.x), bflo(q.y), bfhi(q.y),
                       bflo(q.z), bfhi(q.z), bflo(q.w), bfhi(q.w)};
        float4 bb0 = *(const float4*)(b1 + fl * 8);
        float4 bb1 = *(const float4*)(b1 + fl * 8 + 4);
        float bbv[8] = {bb0.x, bb0.y, bb0.z, bb0.w, bb1.x, bb1.y, bb1.z, bb1.w};
        float o[8];
#pragma unroll
        for (int j = 0; j < 8; j++) o[j] = fmaxf(di * (acc[j] + sv[j]) + bbv[j], 0.f);
        *(float4*)(h1 + (size_t)n * HID + fl * 8)     = make_float4(o[0], o[1], o[2], o[3]);
        *(float4*)(h1 + (size_t)n * HID + fl * 8 + 4) = make_float4(o[4], o[5], o[6], o[7]);
    }
}

// ---------------- layer-2 aggregate + head: wave per node, F=32, bf16 table ---
__global__ __launch_bounds__(256) void agg2_final_kernel(const unsigned short* __restrict__ sorted_src,
                                                         const int* __restrict__ off,
                                                         const float* __restrict__ dinv,
                                                         const unsigned short* __restrict__ hws,
                                                         const float* __restrict__ b2,
                                                         const float* __restrict__ Wh,
                                                         const float* __restrict__ bh,
                                                         float* __restrict__ out, int N) {
    int lane = threadIdx.x & 63;
    int n = blockIdx.x * 4 + (threadIdx.x >> 6);
    if (n >= N) return;
    int g = lane >> 2, fl = lane & 3;  // 16 edge-groups x 4 feature-lanes (8 feats each)
    int start = off[n], end = off[n + 1];
    float acc[8] = {0.f, 0.f, 0.f, 0.f, 0.f, 0.f, 0.f, 0.f};
    for (int i = start + g; i < end; i += 16) {
        int s = sorted_src[i];
        uint4 q = *(const uint4*)(hws + (size_t)s * HID2 + fl * 8);
        acc[0] += bflo(q.x); acc[1] += bfhi(q.x);
        acc[2] += bflo(q.y); acc[3] += bfhi(q.y);
        acc[4] += bflo(q.z); acc[5] += bfhi(q.z);
        acc[6] += bflo(q.w); acc[7] += bfhi(q.w);
    }
#pragma unroll
    for (int m = 4; m <= 32; m <<= 1)
#pragma unroll
        for (int j = 0; j < 8; j++) acc[j] += __shfl_xor(acc[j], m, 64);
    float di = dinv[n];
    uint4 q = *(const uint4*)(hws + (size_t)n * HID2 + fl * 8);
    float sv[8] = {bflo(q.x), bfhi(q.x), bflo(q.y), bfhi(q.y),
                   bflo(q.z), bfhi(q.z), bflo(q.w), bfhi(q.w)};
    float4 bb0 = *(const float4*)(b2 + fl * 8);
    float4 bb1 = *(const float4*)(b2 + fl * 8 + 4);
    float bbv[8] = {bb0.x, bb0.y, bb0.z, bb0.w, bb1.x, bb1.y, bb1.z, bb1.w};
    float4 wv0 = *(const float4*)(Wh + fl * 8);
    float4 wv1 = *(const float4*)(Wh + fl * 8 + 4);
    float wvv[8] = {wv0.x, wv0.y, wv0.z, wv0.w, wv1.x, wv1.y, wv1.z, wv1.w};
    float p = 0.f;
#pragma unroll
    for (int j = 0; j < 8; j++)
        p += fmaxf(di * (acc[j] + sv[j]) + bbv[j], 0.f) * wvv[j];
    p += __shfl_xor(p, 1, 64);
    p += __shfl_xor(p, 2, 64);
    if (lane == 0) out[n] = p + bh[0];
}

extern "C" void kernel_launch(void* const* d_in, const int* in_sizes, int n_in,
                              void* d_out, int out_size, void* d_ws, size_t ws_size,
                              hipStream_t stream) {
    const float* x  = (const float*)d_in[0];
    const int*   ei = (const int*)d_in[1];
    const float* W1 = (const float*)d_in[2];
    const float* b1 = (const float*)d_in[3];
    const float* W2 = (const float*)d_in[4];
    const float* b2 = (const float*)d_in[5];
    const float* Wh = (const float*)d_in[6];
    const float* bh = (const float*)d_in[7];
    float* out = (float*)d_out;

    const int N = N_NODES;
    const int E = in_sizes[1] / 2;
    const int* src = ei;
    const int* dst = ei + E;

    // workspace layout (byte offsets via int units)
    int* ws = (int*)d_ws;
    int*   bhist = ws;                                  // 400
    int*   bbase = bhist + 400;                         // 400
    int*   bcur  = bbase + 400;                         // 400
    int*   off   = bcur + 400;                          // 50048
    float* dinv  = (float*)(off + 50048);               // 50048
    unsigned short* psrc = (unsigned short*)(dinv + 50048);  // E ushort (3.2 MB)
    int*   pdst  = (int*)(psrc + ((E + 7) & ~7));       // E int (6.4 MB)
    unsigned short* xws = (unsigned short*)(pdst + E);  // N*64 bf16 (6.4 MB)
    float* h1    = (float*)(xws + (size_t)N * HID);     // N*64 f32 (12.8 MB)
    unsigned short* hws = xws;                          // alias: xws dead after agg1

    hipMemsetAsync(bhist, 0, NB * sizeof(int), stream);

    int eblocks = (E + CHUNK - 1) / CHUNK;
    coarse_hist_kernel<<<eblocks, 256, 0, stream>>>(dst, bhist, E);
    coarse_scan_kernel<<<1, 256, 0, stream>>>(bhist, bbase, bcur, off, E);
    bin_kernel<<<eblocks, 256, 0, stream>>>(src, dst, bcur, psrc, pdst, E);
    fine_kernel<<<NB, 256, 0, stream>>>(psrc, pdst, bbase, off, dinv, N);

    // layer 1
    gemm_rb_bf16_kernel<IN_CH, HID, 32><<<(N + 31) / 32, 256, 0, stream>>>(x, W1, dinv, xws, N);
    agg1_kernel<<<(N + 3) / 4, 256, 0, stream>>>(psrc, off, dinv, xws, b1, h1, N);

    // layer 2 + head
    gemm_rb_bf16_kernel<HID, HID2, 64><<<(N + 63) / 64, 256, 0, stream>>>(h1, W2, dinv, hws, N);
    agg2_final_kernel<<<(N + 3) / 4, 256, 0, stream>>>(psrc, off, dinv, hws, b2, Wh, bh, out, N);
}

// Round 6
// 237.288 us; speedup vs baseline: 9.2928x; 1.0606x over previous
//
#include <hip/hip_runtime.h>
#include <hip/hip_bf16.h>

#define N_NODES 50000
#define IN_CH 128
#define HID 64
#define HID2 32

constexpr int NB = 391;      // coarse buckets of 128 nodes: ceil(50000/128)
constexpr int CHUNK = 4096;  // edges per binning block
constexpr int CAP = 5120;    // fixed window per bucket (mean 4096, +16 sigma safe)
#define FPSCALE 524288.0f    // 2^19 fixed-point scale (folded into bf16 table)
#define FPINV   0x1p-19f

__device__ __forceinline__ unsigned short f2bf(float f) {
    union { float f; unsigned u; } v; v.f = f;
    unsigned r = v.u + 0x7fff + ((v.u >> 16) & 1);  // RNE
    return (unsigned short)(r >> 16);
}
__device__ __forceinline__ float bflo(unsigned d) {  // low 16 bits -> fp32
    union { unsigned u; float f; } v; v.u = d << 16; return v.f;
}
__device__ __forceinline__ float bfhi(unsigned d) {  // high 16 bits -> fp32
    union { unsigned u; float f; } v; v.u = d & 0xffff0000u; return v.f;
}

// ---- A: bin edges into fixed per-bucket windows (bucket-grouped writes) ----
// psrc[i*CAP + p] = src (ushort);  pbyte[...] = dst & 127 (node-low7)
__global__ __launch_bounds__(256) void bin_kernel(const int* __restrict__ src,
                                                  const int* __restrict__ dst,
                                                  int* __restrict__ bcur,
                                                  unsigned short* __restrict__ psrc,
                                                  unsigned char* __restrict__ pbyte, int E) {
    __shared__ int hist[NB], lbase[NB], gbase[NB], lcur[NB];
    __shared__ unsigned short outs[CHUNK];
    __shared__ int outd[CHUNK];
    int tid = threadIdx.x;
    int base = blockIdx.x * CHUNK;
    int cnt = min(CHUNK, E - base);
    for (int i = tid; i < NB; i += 256) hist[i] = 0;
    int es[CHUNK / 256], ed[CHUNK / 256];
    __syncthreads();
#pragma unroll
    for (int k = 0; k < CHUNK / 256; k++) {
        int e = base + k * 256 + tid;
        if (e < E) {
            es[k] = src[e];
            ed[k] = dst[e];
            atomicAdd(&hist[ed[k] >> 7], 1);
        }
    }
    __syncthreads();
    if (tid == 0) {
        int run = 0;
        for (int b = 0; b < NB; b++) { int t = hist[b]; lbase[b] = run; run += t; }
    }
    __syncthreads();
    for (int i = tid; i < NB; i += 256) {
        gbase[i] = i * CAP + (hist[i] ? atomicAdd(&bcur[i], hist[i]) : 0);
        lcur[i] = lbase[i];
    }
    __syncthreads();
#pragma unroll
    for (int k = 0; k < CHUNK / 256; k++) {
        int e = base + k * 256 + tid;
        if (e < E) {
            int b = ed[k] >> 7;
            int p = atomicAdd(&lcur[b], 1);
            outs[p] = (unsigned short)es[k];
            outd[p] = ed[k];
        }
    }
    __syncthreads();
#pragma unroll
    for (int k = 0; k < CHUNK / 256; k++) {
        int i = k * 256 + tid;
        if (i < cnt) {
            int d = outd[i];
            int b = d >> 7;
            int gp = gbase[b] + (i - lbase[b]);
            psrc[gp] = outs[i];
            pbyte[gp] = (unsigned char)(d & 127);
        }
    }
}

// ---- B: per-bucket fine pass: group window by node (any order — sums are int,
//      order-independent). Emits CSR-in-window psrc, off, len, dinv. ----
__global__ __launch_bounds__(256) void fine_kernel(unsigned short* __restrict__ psrc,
                                                   const unsigned char* __restrict__ pbyte,
                                                   const int* __restrict__ bcur,
                                                   int* __restrict__ off,
                                                   unsigned short* __restrict__ len,
                                                   float* __restrict__ dinv, int N) {
    __shared__ unsigned short lsrc[CAP];
    __shared__ unsigned char lb[CAP];
    __shared__ int fh[128], fb[128], fc[128];
    int b = blockIdx.x, tid = threadIdx.x;
    int gb = b * CAP;
    int cnt = min(bcur[b], CAP);
    if (tid < 128) fh[tid] = 0;
    __syncthreads();
    for (int i = tid; i < cnt; i += 256) {
        lsrc[i] = psrc[gb + i];
        int dl = pbyte[gb + i];
        lb[i] = (unsigned char)dl;
        atomicAdd(&fh[dl], 1);
    }
    __syncthreads();
    if (tid == 0) {
        int run = 0;
        for (int j = 0; j < 128; j++) { int t = fh[j]; fb[j] = run; run += t; }
    }
    __syncthreads();
    if (tid < 128) {
        fc[tid] = fb[tid];
        int node = (b << 7) + tid;
        if (node < N) {
            off[node] = gb + fb[tid];
            len[node] = (unsigned short)fh[tid];
            dinv[node] = rsqrtf((float)fh[tid] + 1.0f);
        }
    }
    __syncthreads();
    for (int i = tid; i < cnt; i += 256) {
        int p = atomicAdd(&fc[lb[i]], 1);
        psrc[gb + p] = lsrc[i];
    }
}

// ---- register-blocked GEMM, 8 nodes/thread, fused dinv*2^19 bf16 epilogue ----
// out_bf16[n][j] = bf16( dinv[n] * 2^19 * (X@W)[n][j] )
template <int K, int J, int NPB>
__global__ __launch_bounds__(256) void gemm_rb_bf16_kernel(const float* __restrict__ X,
                                                           const float* __restrict__ W,
                                                           const float* __restrict__ dinv,
                                                           unsigned short* __restrict__ out, int N) {
    constexpr int QJ = J / 4, GR = 256 / QJ, NPT = NPB / GR;
    __shared__ float Ws[K * J];
    __shared__ float xs[NPB][K + 1];
    int tid = threadIdx.x;
    for (int i = tid; i < K * J / 4; i += 256) ((float4*)Ws)[i] = ((const float4*)W)[i];
    int n0 = blockIdx.x * NPB;
    for (int i = tid; i < NPB * (K / 4); i += 256) {
        int r = i / (K / 4), c = i % (K / 4);
        int n = n0 + r;
        float4 v = make_float4(0.f, 0.f, 0.f, 0.f);
        if (n < N) v = ((const float4*)(X + (size_t)n * K))[c];
        *(float4*)&xs[r][c * 4] = v;
    }
    __syncthreads();
    int q = tid % QJ, g = (tid / QJ) * NPT;
    float acc[NPT][4];
#pragma unroll
    for (int t = 0; t < NPT; t++) { acc[t][0] = acc[t][1] = acc[t][2] = acc[t][3] = 0.f; }
    for (int k = 0; k < K; k++) {
        float4 w = *(const float4*)&Ws[k * J + q * 4];
#pragma unroll
        for (int t = 0; t < NPT; t++) {
            float xv = xs[g + t][k];
            acc[t][0] += xv * w.x; acc[t][1] += xv * w.y;
            acc[t][2] += xv * w.z; acc[t][3] += xv * w.w;
        }
    }
#pragma unroll
    for (int t = 0; t < NPT; t++) {
        int n = n0 + g + t;
        if (n < N) {
            float d0 = dinv[n] * FPSCALE;
            ushort4 o = make_ushort4(f2bf(acc[t][0] * d0), f2bf(acc[t][1] * d0),
                                     f2bf(acc[t][2] * d0), f2bf(acc[t][3] * d0));
            *(ushort4*)(out + (size_t)n * J + q * 4) = o;
        }
    }
}

// ---- layer-1 aggregate: wave/node, F=64, bf16 table, int32 fixed-point sums --
// h1[n] = relu( dinv[n]*2^-19 * (Σ_s t[s] + t[n]) + b1 ),  t = 2^19*dinv*xw (bf16)
__global__ __launch_bounds__(256) void agg1_kernel(const unsigned short* __restrict__ sorted_src,
                                                   const int* __restrict__ off,
                                                   const unsigned short* __restrict__ len,
                                                   const float* __restrict__ dinv,
                                                   const unsigned short* __restrict__ xws,
                                                   const float* __restrict__ b1,
                                                   float* __restrict__ h1, int N) {
    int lane = threadIdx.x & 63;
    int n = blockIdx.x * 4 + (threadIdx.x >> 6);
    if (n >= N) return;
    int g = lane >> 3, fl = lane & 7;  // 8 edge-groups x 8 feature-lanes
    int start = off[n], end = start + len[n];
    int acc[8] = {0, 0, 0, 0, 0, 0, 0, 0};
    for (int i = start + g; i < end; i += 8) {
        int s = sorted_src[i];
        uint4 q = *(const uint4*)(xws + (size_t)s * HID + fl * 8);
        acc[0] += (int)bflo(q.x); acc[1] += (int)bfhi(q.x);
        acc[2] += (int)bflo(q.y); acc[3] += (int)bfhi(q.y);
        acc[4] += (int)bflo(q.z); acc[5] += (int)bfhi(q.z);
        acc[6] += (int)bflo(q.w); acc[7] += (int)bfhi(q.w);
    }
#pragma unroll
    for (int m = 8; m <= 32; m <<= 1)
#pragma unroll
        for (int j = 0; j < 8; j++) acc[j] += __shfl_xor(acc[j], m, 64);
    if (g == 0) {
        float dis = dinv[n] * FPINV;
        uint4 q = *(const uint4*)(xws + (size_t)n * HID + fl * 8);
        int sv[8] = {(int)bflo(q.x), (int)bfhi(q.x), (int)bflo(q.y), (int)bfhi(q.y),
                     (int)bflo(q.z), (int)bfhi(q.z), (int)bflo(q.w), (int)bfhi(q.w)};
        float4 bb0 = *(const float4*)(b1 + fl * 8);
        float4 bb1 = *(const float4*)(b1 + fl * 8 + 4);
        float bbv[8] = {bb0.x, bb0.y, bb0.z, bb0.w, bb1.x, bb1.y, bb1.z, bb1.w};
        float o[8];
#pragma unroll
        for (int j = 0; j < 8; j++)
            o[j] = fmaxf((float)(acc[j] + sv[j]) * dis + bbv[j], 0.f);
        *(float4*)(h1 + (size_t)n * HID + fl * 8)     = make_float4(o[0], o[1], o[2], o[3]);
        *(float4*)(h1 + (size_t)n * HID + fl * 8 + 4) = make_float4(o[4], o[5], o[6], o[7]);
    }
}

// ---- layer-2 aggregate + head: wave/node, F=32, bf16 table, int32 sums -------
__global__ __launch_bounds__(256) void agg2_final_kernel(const unsigned short* __restrict__ sorted_src,
                                                         const int* __restrict__ off,
                                                         const unsigned short* __restrict__ len,
                                                         const float* __restrict__ dinv,
                                                         const unsigned short* __restrict__ hws,
                                                         const float* __restrict__ b2,
                                                         const float* __restrict__ Wh,
                                                         const float* __restrict__ bh,
                                                         float* __restrict__ out, int N) {
    int lane = threadIdx.x & 63;
    int n = blockIdx.x * 4 + (threadIdx.x >> 6);
    if (n >= N) return;
    int g = lane >> 2, fl = lane & 3;  // 16 edge-groups x 4 feature-lanes (8 feats each)
    int start = off[n], end = start + len[n];
    int acc[8] = {0, 0, 0, 0, 0, 0, 0, 0};
    for (int i = start + g; i < end; i += 16) {
        int s = sorted_src[i];
        uint4 q = *(const uint4*)(hws + (size_t)s * HID2 + fl * 8);
        acc[0] += (int)bflo(q.x); acc[1] += (int)bfhi(q.x);
        acc[2] += (int)bflo(q.y); acc[3] += (int)bfhi(q.y);
        acc[4] += (int)bflo(q.z); acc[5] += (int)bfhi(q.z);
        acc[6] += (int)bflo(q.w); acc[7] += (int)bfhi(q.w);
    }
#pragma unroll
    for (int m = 4; m <= 32; m <<= 1)
#pragma unroll
        for (int j = 0; j < 8; j++) acc[j] += __shfl_xor(acc[j], m, 64);
    float dis = dinv[n] * FPINV;
    uint4 q = *(const uint4*)(hws + (size_t)n * HID2 + fl * 8);
    int sv[8] = {(int)bflo(q.x), (int)bfhi(q.x), (int)bflo(q.y), (int)bfhi(q.y),
                 (int)bflo(q.z), (int)bfhi(q.z), (int)bflo(q.w), (int)bfhi(q.w)};
    float4 bb0 = *(const float4*)(b2 + fl * 8);
    float4 bb1 = *(const float4*)(b2 + fl * 8 + 4);
    float bbv[8] = {bb0.x, bb0.y, bb0.z, bb0.w, bb1.x, bb1.y, bb1.z, bb1.w};
    float4 wv0 = *(const float4*)(Wh + fl * 8);
    float4 wv1 = *(const float4*)(Wh + fl * 8 + 4);
    float wvv[8] = {wv0.x, wv0.y, wv0.z, wv0.w, wv1.x, wv1.y, wv1.z, wv1.w};
    float p = 0.f;
#pragma unroll
    for (int j = 0; j < 8; j++)
        p += fmaxf((float)(acc[j] + sv[j]) * dis + bbv[j], 0.f) * wvv[j];
    p += __shfl_xor(p, 1, 64);
    p += __shfl_xor(p, 2, 64);
    if (lane == 0) out[n] = p + bh[0];
}

extern "C" void kernel_launch(void* const* d_in, const int* in_sizes, int n_in,
                              void* d_out, int out_size, void* d_ws, size_t ws_size,
                              hipStream_t stream) {
    const float* x  = (const float*)d_in[0];
    const int*   ei = (const int*)d_in[1];
    const float* W1 = (const float*)d_in[2];
    const float* b1 = (const float*)d_in[3];
    const float* W2 = (const float*)d_in[4];
    const float* b2 = (const float*)d_in[5];
    const float* Wh = (const float*)d_in[6];
    const float* bh = (const float*)d_in[7];
    float* out = (float*)d_out;

    const int N = N_NODES;
    const int E = in_sizes[1] / 2;
    const int* src = ei;
    const int* dst = ei + E;

    // workspace layout (all offsets 16B-aligned)
    int* ws = (int*)d_ws;
    int*            bcur  = ws;                                   // 512 ints
    int*            off   = bcur + 512;                           // 50048 ints
    unsigned short* len   = (unsigned short*)(off + 50048);       // 50048 ushort
    float*          dinv  = (float*)((int*)len + 25024);          // 50048 floats
    unsigned short* psrc  = (unsigned short*)(dinv + 50048);      // NB*CAP ushort (4 MB)
    unsigned char*  pbyte = (unsigned char*)(psrc + (size_t)NB * CAP);  // NB*CAP bytes (2 MB)
    unsigned short* xws   = (unsigned short*)(pbyte + (size_t)NB * CAP);// N*64 bf16 (6.4 MB)
    float*          h1    = (float*)(xws + (size_t)N * HID);      // N*64 f32 (12.8 MB)
    unsigned short* hws   = xws;                                  // alias: xws dead after agg1

    hipMemsetAsync(bcur, 0, NB * sizeof(int), stream);

    int eblocks = (E + CHUNK - 1) / CHUNK;
    bin_kernel<<<eblocks, 256, 0, stream>>>(src, dst, bcur, psrc, pbyte, E);
    fine_kernel<<<NB, 256, 0, stream>>>(psrc, pbyte, bcur, off, len, dinv, N);

    // layer 1
    gemm_rb_bf16_kernel<IN_CH, HID, 128><<<(N + 127) / 128, 256, 0, stream>>>(x, W1, dinv, xws, N);
    agg1_kernel<<<(N + 3) / 4, 256, 0, stream>>>(psrc, off, len, dinv, xws, b1, h1, N);

    // layer 2 + head
    gemm_rb_bf16_kernel<HID, HID2, 256><<<(N + 255) / 256, 256, 0, stream>>>(h1, W2, dinv, hws, N);
    agg2_final_kernel<<<(N + 3) / 4, 256, 0, stream>>>(psrc, off, len, dinv, hws, b2, Wh, bh, out, N);
}